// Round 10
// baseline (442.446 us; speedup 1.0000x reference)
//
#include <hip/hip_runtime.h>
#include <hip/hip_bf16.h>
#include <hip/hip_cooperative_groups.h>

namespace cg = cooperative_groups;

#define Tsz 2048
#define Csz 1024

typedef short s8v __attribute__((ext_vector_type(8)));
typedef short s4v __attribute__((ext_vector_type(4)));
typedef float f4v __attribute__((ext_vector_type(4)));

#define QSCALE (0.125f * 1.44269504088896f)  // 1/sqrt(64) * log2(e), folded into Q

// fast bf16 round (bits+0x8000)>>16
__device__ __forceinline__ unsigned short bfr(float x) {
    return (unsigned short)((__builtin_bit_cast(unsigned, x) + 0x8000u) >> 16);
}
__device__ __forceinline__ unsigned pack2_rn(float a, float b) {
    const unsigned ua = __builtin_bit_cast(unsigned, a) + 0x8000u;
    const unsigned ub = __builtin_bit_cast(unsigned, b) + 0x8000u;
    return (ua >> 16) | (ub & 0xFFFF0000u);
}

__device__ __forceinline__ void gload_lds(const void* g, void* l) {
    __builtin_amdgcn_global_load_lds(
        (const __attribute__((address_space(1))) void*)g,
        (__attribute__((address_space(3))) void*)l, 16, 0, 0);
}

__device__ __forceinline__ void cvt_range(const float* __restrict__ in,
                                          short* __restrict__ out,
                                          int n4, int gtid, int gstride) {
    for (int i = gtid; i < n4; i += gstride) {
        float4 v = ((const float4*)in)[i];
        int2 o;
        o.x = (int)pack2_rn(v.x, v.y);
        o.y = (int)pack2_rn(v.z, v.w);
        ((int2*)out)[i] = o;
    }
}

// ============ single cooperative kernel: cvt -> QKV -> attn -> proj ============
// 256 blocks x 512 threads, 1 block/CU co-resident; 55296 B LDS arena shared
// across phases; grid.sync() + device fence between phases.
__global__ __launch_bounds__(512, 2) void mega(
    const float* __restrict__ x,
    const float* __restrict__ Wq, const float* __restrict__ bq,
    const float* __restrict__ Wk, const float* __restrict__ bk,
    const float* __restrict__ Wv, const float* __restrict__ bv,
    const float* __restrict__ Wp, const float* __restrict__ bp,
    float* __restrict__ out,
    short* __restrict__ Xb, short* __restrict__ Wqb, short* __restrict__ Wkb,
    short* __restrict__ Wvb, short* __restrict__ Wpb,
    short* __restrict__ Qb, short* __restrict__ Kb, short* __restrict__ Vtb,
    short* __restrict__ Yb)
{
    __shared__ __align__(16) short smem[27648];   // 55296 B arena
    cg::grid_group grid = cg::this_grid();

    const int tid = threadIdx.x, lane = tid & 63, wave = tid >> 6;
    const int ln = lane & 15, hi = lane >> 4;
    const int blk = blockIdx.x;

    // ---------------- Phase 1: fp32 -> bf16 ----------------
    {
        const int gtid = blk * 512 + tid, gs = 256 * 512;
        cvt_range(x,  Xb,  1048576, gtid, gs);   // 4.19M floats
        cvt_range(Wq, Wqb, 262144, gtid, gs);
        cvt_range(Wk, Wkb, 262144, gtid, gs);
        cvt_range(Wv, Wvb, 262144, gtid, gs);
        cvt_range(Wp, Wpb, 262144, gtid, gs);
    }
    __threadfence();
    grid.sync();

    // ---------------- Phase 2: fused QKV GEMM (shared A staging) ----------------
    // tile 128m x 128n; 8 waves, wave = 64m x 32n; 3 GEMMs share the A tile.
    {
        short* Ash = smem;            // [128][32]
        short* Bq_ = smem + 4096;
        short* Bk_ = smem + 8192;
        short* Bv_ = smem + 12288;
        const int m0 = (blk >> 3) * 128, n0 = (blk & 7) * 128;
        const int wm = (wave >> 2) * 64, wn = (wave & 3) * 32;

        const short* Ag = Xb  + (size_t)(m0 + (tid >> 2)) * Csz + (tid & 3) * 8;
        const short* Qg = Wqb + (size_t)(n0 + (tid >> 2)) * Csz + (tid & 3) * 8;
        const short* Kgp = Wkb + (size_t)(n0 + (tid >> 2)) * Csz + (tid & 3) * 8;
        const short* Vg = Wvb + (size_t)(n0 + (tid >> 2)) * Csz + (tid & 3) * 8;

        f4v aq[4][2], ak[4][2], av[4][2];
        #pragma unroll
        for (int mt = 0; mt < 4; mt++)
            #pragma unroll
            for (int nt = 0; nt < 2; nt++)
                #pragma unroll
                for (int i = 0; i < 4; i++) { aq[mt][nt][i] = 0.f; ak[mt][nt][i] = 0.f; av[mt][nt][i] = 0.f; }

        for (int k0 = 0; k0 < Csz; k0 += 32) {
            __syncthreads();
            gload_lds(Ag + k0, Ash + tid * 8);
            gload_lds(Qg + k0, Bq_ + tid * 8);
            gload_lds(Kgp + k0, Bk_ + tid * 8);
            gload_lds(Vg + k0, Bv_ + tid * 8);
            __syncthreads();

            s8v af[4];
            #pragma unroll
            for (int mt = 0; mt < 4; mt++)
                af[mt] = *(const s8v*)(Ash + (wm + mt * 16 + ln) * 32 + hi * 8);
            #pragma unroll
            for (int nt = 0; nt < 2; nt++) {
                const int ro = (wn + nt * 16 + ln) * 32 + hi * 8;
                const s8v fq = *(const s8v*)(Bq_ + ro);
                const s8v fk = *(const s8v*)(Bk_ + ro);
                const s8v fv = *(const s8v*)(Bv_ + ro);
                #pragma unroll
                for (int mt = 0; mt < 4; mt++) {
                    aq[mt][nt] = __builtin_amdgcn_mfma_f32_16x16x32_bf16(af[mt], fq, aq[mt][nt], 0, 0, 0);
                    ak[mt][nt] = __builtin_amdgcn_mfma_f32_16x16x32_bf16(af[mt], fk, ak[mt][nt], 0, 0, 0);
                    av[mt][nt] = __builtin_amdgcn_mfma_f32_16x16x32_bf16(af[mt], fv, av[mt][nt], 0, 0, 0);
                }
            }
        }

        // epilogue Q, K (direct [B,T,C] bf16 stores)
        #pragma unroll
        for (int nt = 0; nt < 2; nt++) {
            const int col = n0 + wn + nt * 16 + ln;
            const float bqv = bq[col], bkv = bk[col];
            #pragma unroll
            for (int mt = 0; mt < 4; mt++) {
                const int row0 = m0 + wm + mt * 16 + hi * 4;
                #pragma unroll
                for (int i = 0; i < 4; i++) {
                    Qb[(size_t)(row0 + i) * Csz + col] = (short)bfr((aq[mt][nt][i] + bqv) * QSCALE);
                    Kb[(size_t)(row0 + i) * Csz + col] = (short)bfr(ak[mt][nt][i] + bkv);
                }
            }
        }
        // epilogue V: LDS transpose -> Vt[(b*1024+ch)*T + t], coalesced 16B stores
        {
            short* TR = smem + 16384;   // [64][72]
            float bvv[2];
            #pragma unroll
            for (int nt = 0; nt < 2; nt++) bvv[nt] = bv[n0 + wn + nt * 16 + ln];
            const int b_ = m0 >> 11, t0 = m0 & 2047;
            #pragma unroll
            for (int ph = 0; ph < 4; ph++) {
                const int mh = ph >> 1, nh = ph & 1;
                __syncthreads();
                if ((wave >> 2) == mh && ((wave >> 1) & 1) == nh) {
                    #pragma unroll
                    for (int mt = 0; mt < 4; mt++)
                        #pragma unroll
                        for (int nt = 0; nt < 2; nt++) {
                            int2 pk;
                            pk.x = (int)pack2_rn(av[mt][nt][0] + bvv[nt], av[mt][nt][1] + bvv[nt]);
                            pk.y = (int)pack2_rn(av[mt][nt][2] + bvv[nt], av[mt][nt][3] + bvv[nt]);
                            *(int2*)(TR + ((wave & 1) * 32 + nt * 16 + ln) * 72 + mt * 16 + hi * 4) = pk;
                        }
                }
                __syncthreads();
                const int chl = tid >> 3, seg = tid & 7;
                const s8v r = *(const s8v*)(TR + chl * 72 + seg * 8);
                *(s8v*)(Vtb + (size_t)(b_ * 1024 + n0 + nh * 64 + chl) * Tsz + t0 + mh * 64 + seg * 8) = r;
            }
        }
    }
    __threadfence();
    grid.sync();

    // ---------------- Phase 3: flash attention (attn9 structure) ----------------
    {
        short* Ksh = smem;              // [2][64*72]
        short* Vsh = smem + 9216;       // [2][64*72]
        short* Pq  = smem + 18432 + wave * 1152;  // per-wave [16][72]

        const int wv = wave & 3, g = wave >> 2;
        const int p = blk & 7;
        const int bh = blk >> 3;
        const int qts[2] = { g ? 15 - p : p, g ? 16 + p : 31 - p };  // light, heavy
        const size_t base = (size_t)(bh >> 4) * Tsz * Csz + (size_t)(bh & 15) * 64;
        const size_t vtbase = (size_t)bh * 64 * Tsz;
        const int qrel = wv * 16 + ln;

        s8v qf[2][2];
        #pragma unroll
        for (int t = 0; t < 2; t++)
            #pragma unroll
            for (int kk = 0; kk < 2; kk++)
                qf[t][kk] = *(const s8v*)(Qb + base + (size_t)(qts[t] * 64 + qrel) * Csz + kk * 32 + hi * 8);

        f4v o[2][4];
        float lsum[2] = {0.f, 0.f};
        #pragma unroll
        for (int t = 0; t < 2; t++)
            #pragma unroll
            for (int dt = 0; dt < 4; dt++)
                #pragma unroll
                for (int i = 0; i < 4; i++) o[t][dt][i] = 0.f;

        const int sr = tid >> 3, sc = (tid & 7) * 8;
        const short* Kp = Kb + base + (size_t)sr * Csz + sc;
        const short* Vp = Vtb + vtbase + (size_t)sr * Tsz + sc;
        const int swo = sr * 72 + sc;

        const int nkb = 32 - p;

        s8v kR = *(const s8v*)(Kp);
        s8v vR = *(const s8v*)(Vp);
        *(s8v*)(Ksh + swo) = kR;
        *(s8v*)(Vsh + swo) = vR;
        kR = *(const s8v*)(Kp + (size_t)64 * Csz);
        vR = *(const s8v*)(Vp + 64);
        __syncthreads();

        for (int kb = 0; kb < nkb; kb++) {
            const int buf = kb & 1;
            if (kb + 1 < nkb) {
                *(s8v*)(Ksh + (buf ^ 1) * 4608 + swo) = kR;
                *(s8v*)(Vsh + (buf ^ 1) * 4608 + swo) = vR;
                const int knx = (kb + 2 < nkb) ? (kb + 2) * 64 : (nkb - 1) * 64;
                kR = *(const s8v*)(Kp + (size_t)knx * Csz);
                vR = *(const s8v*)(Vp + knx);
            }

            s8v kf[2][4], vf[2][4];
            #pragma unroll
            for (int nt = 0; nt < 4; nt++)
                #pragma unroll
                for (int kk = 0; kk < 2; kk++) {
                    kf[kk][nt] = *(const s8v*)(Ksh + buf * 4608 + (nt * 16 + ln) * 72 + kk * 32 + hi * 8);
                    vf[kk][nt] = *(const s8v*)(Vsh + buf * 4608 + (nt * 16 + ln) * 72 + kk * 32 + hi * 8);
                }

            #pragma unroll
            for (int t = 0; t < 2; t++) {
                if (kb > qts[t]) continue;         // wave-uniform
                const bool dg = (kb == qts[t]);

                f4v s[4];
                #pragma unroll
                for (int nt = 0; nt < 4; nt++) {
                    #pragma unroll
                    for (int i = 0; i < 4; i++) s[nt][i] = 0.f;
                    s[nt] = __builtin_amdgcn_mfma_f32_16x16x32_bf16(kf[0][nt], qf[t][0], s[nt], 0, 0, 0);
                    s[nt] = __builtin_amdgcn_mfma_f32_16x16x32_bf16(kf[1][nt], qf[t][1], s[nt], 0, 0, 0);
                }

                #pragma unroll
                for (int nt = 0; nt < 4; nt++) {
                    float pv[4];
                    #pragma unroll
                    for (int i = 0; i < 4; i++) pv[i] = exp2f(s[nt][i]);
                    if (dg) {
                        const int kr = nt * 16 + hi * 4;
                        #pragma unroll
                        for (int i = 0; i < 4; i++)
                            if (kr + i > qrel) pv[i] = 0.f;
                    }
                    lsum[t] += (pv[0] + pv[1]) + (pv[2] + pv[3]);
                    int2 w;
                    w.x = (int)pack2_rn(pv[0], pv[1]);
                    w.y = (int)pack2_rn(pv[2], pv[3]);
                    *(int2*)(Pq + ln * 72 + nt * 16 + hi * 4) = w;
                }
                const s8v pb0 = *(const s8v*)(Pq + ln * 72 + hi * 8);
                const s8v pb1 = *(const s8v*)(Pq + ln * 72 + 32 + hi * 8);

                #pragma unroll
                for (int dt = 0; dt < 4; dt++) {
                    o[t][dt] = __builtin_amdgcn_mfma_f32_16x16x32_bf16(vf[0][dt], pb0, o[t][dt], 0, 0, 0);
                    o[t][dt] = __builtin_amdgcn_mfma_f32_16x16x32_bf16(vf[1][dt], pb1, o[t][dt], 0, 0, 0);
                }
            }
            __syncthreads();
        }

        #pragma unroll
        for (int t = 0; t < 2; t++) {
            float l = lsum[t];
            l += __shfl_xor(l, 16);
            l += __shfl_xor(l, 32);
            const float inv = 1.0f / l;
            const int qrow = qts[t] * 64 + qrel;
            #pragma unroll
            for (int dt = 0; dt < 4; dt++) {
                int2 w;
                w.x = (int)pack2_rn(o[t][dt][0] * inv, o[t][dt][1] * inv);
                w.y = (int)pack2_rn(o[t][dt][2] * inv, o[t][dt][3] * inv);
                *(int2*)(Yb + base + (size_t)qrow * Csz + dt * 16 + hi * 4) = w;
            }
        }
    }
    __threadfence();
    grid.sync();

    // ---------------- Phase 4: output projection (f32 out) ----------------
    {
        short* Ash = smem;
        short* Bsh = smem + 4096;
        const int m0 = (blk >> 3) * 128, n0 = (blk & 7) * 128;
        const int wm = (wave >> 2) * 64, wn = (wave & 3) * 32;

        const short* Ag = Yb  + (size_t)(m0 + (tid >> 2)) * Csz + (tid & 3) * 8;
        const short* Bg = Wpb + (size_t)(n0 + (tid >> 2)) * Csz + (tid & 3) * 8;

        f4v acc[4][2];
        #pragma unroll
        for (int mt = 0; mt < 4; mt++)
            #pragma unroll
            for (int nt = 0; nt < 2; nt++)
                #pragma unroll
                for (int i = 0; i < 4; i++) acc[mt][nt][i] = 0.f;

        for (int k0 = 0; k0 < Csz; k0 += 32) {
            __syncthreads();
            gload_lds(Ag + k0, Ash + tid * 8);
            gload_lds(Bg + k0, Bsh + tid * 8);
            __syncthreads();

            s8v af[4], bfr_[2];
            #pragma unroll
            for (int mt = 0; mt < 4; mt++)
                af[mt] = *(const s8v*)(Ash + (wm + mt * 16 + ln) * 32 + hi * 8);
            #pragma unroll
            for (int nt = 0; nt < 2; nt++)
                bfr_[nt] = *(const s8v*)(Bsh + (wn + nt * 16 + ln) * 32 + hi * 8);
            #pragma unroll
            for (int mt = 0; mt < 4; mt++)
                #pragma unroll
                for (int nt = 0; nt < 2; nt++)
                    acc[mt][nt] = __builtin_amdgcn_mfma_f32_16x16x32_bf16(af[mt], bfr_[nt], acc[mt][nt], 0, 0, 0);
        }

        #pragma unroll
        for (int nt = 0; nt < 2; nt++) {
            const int col = n0 + wn + nt * 16 + ln;
            const float bvv = bp[col];
            #pragma unroll
            for (int mt = 0; mt < 4; mt++)
                #pragma unroll
                for (int i = 0; i < 4; i++)
                    out[(size_t)(m0 + wm + mt * 16 + hi * 4 + i) * Csz + col] = acc[mt][nt][i] + bvv;
        }
    }
}

extern "C" void kernel_launch(void* const* d_in, const int* in_sizes, int n_in,
                              void* d_out, int out_size, void* d_ws, size_t ws_size,
                              hipStream_t stream) {
    const float* x  = (const float*)d_in[0];
    const float* Wq = (const float*)d_in[1];
    const float* bq = (const float*)d_in[2];
    const float* Wk = (const float*)d_in[3];
    const float* bk = (const float*)d_in[4];
    const float* Wv = (const float*)d_in[5];
    const float* bv = (const float*)d_in[6];
    const float* Wp = (const float*)d_in[7];
    const float* bp = (const float*)d_in[8];
    float* outp = (float*)d_out;

    char* ws = (char*)d_ws;
    short* Xb  = (short*)(ws);                 // 8 MB
    short* Wqb = (short*)(ws + (8u  << 20));   // 2 MB each
    short* Wkb = (short*)(ws + (10u << 20));
    short* Wvb = (short*)(ws + (12u << 20));
    short* Wpb = (short*)(ws + (14u << 20));
    short* Qb  = (short*)(ws + (16u << 20));   // 8 MB each
    short* Kb  = (short*)(ws + (24u << 20));
    short* Vtb = (short*)(ws + (32u << 20));   // V transposed per head [B*H*64, T]
    short* Yb  = (short*)(ws + (40u << 20));

    void* kargs[] = {
        (void*)&x, (void*)&Wq, (void*)&bq, (void*)&Wk, (void*)&bk,
        (void*)&Wv, (void*)&bv, (void*)&Wp, (void*)&bp, (void*)&outp,
        (void*)&Xb, (void*)&Wqb, (void*)&Wkb, (void*)&Wvb, (void*)&Wpb,
        (void*)&Qb, (void*)&Kb, (void*)&Vtb, (void*)&Yb
    };
    hipLaunchCooperativeKernel((const void*)mega, dim3(256), dim3(512), kargs, 0, stream);
}